// Round 3
// baseline (289.470 us; speedup 1.0000x reference)
//
#include <hip/hip_runtime.h>
#include <cmath>

typedef __bf16 bf16_t;
typedef __attribute__((ext_vector_type(8))) __bf16 bf16x8;
typedef __attribute__((ext_vector_type(4))) __bf16 bf16x4;
typedef __attribute__((ext_vector_type(4))) float f32x4;

#define RMS_EPS 1.1920929e-07f
#define KV_SCALE 0.04419417382415922f   // 1/sqrt(512)

__device__ __forceinline__ void gload16(const void* g, void* l) {
  __builtin_amdgcn_global_load_lds((const __attribute__((address_space(1))) void*)g,
                                   (__attribute__((address_space(3))) void*)l, 16, 0, 0);
}

// ---------- all 5 weight casts in one launch: grid (1024, 5) x 256 ----------
__global__ __launch_bounds__(256) void cast_all(const float* __restrict__ s0,
                                                const float* __restrict__ s1,
                                                const float* __restrict__ s2,
                                                const float* __restrict__ s3,
                                                const float* __restrict__ s4,
                                                bf16_t* __restrict__ d) {
  const float* srcs[5] = {s0, s1, s2, s3, s4};
  const int which = blockIdx.y;
  const float* src = srcs[which];
  bf16_t* dst = d + ((size_t)which << 20);
  int i = (blockIdx.x * 256 + threadIdx.x) * 4;
  float4 v = *(const float4*)(src + i);
  bf16x4 o;
  o[0] = (bf16_t)v.x; o[1] = (bf16_t)v.y; o[2] = (bf16_t)v.z; o[3] = (bf16_t)v.w;
  *(bf16x4*)(dst + i) = o;
}

__global__ void concat_bias(const float* __restrict__ bq, const float* __restrict__ bk,
                            const float* __restrict__ bv, float* __restrict__ dst) {
  int i = blockIdx.x * 256 + threadIdx.x;   // grid 12*256 = 3072
  float v;
  if (i < 1024) v = bq[i];
  else if (i < 2048) v = bk[i - 1024];
  else v = bv[i - 2048];
  dst[i] = v;
}

// ---------- RMSNorm(x, g1) -> bf16, one block per row of 1024 ----------
__global__ __launch_bounds__(256) void rmsnorm_x(const float* __restrict__ x,
                                                 const float* __restrict__ g,
                                                 bf16_t* __restrict__ xn) {
  const int m = blockIdx.x, t = threadIdx.x;
  const float4 v = ((const float4*)(x + (size_t)m * 1024))[t];
  float ss = v.x * v.x + v.y * v.y + v.z * v.z + v.w * v.w;
  #pragma unroll
  for (int o = 1; o < 64; o <<= 1) ss += __shfl_xor(ss, o);
  __shared__ float red[4];
  if ((t & 63) == 0) red[t >> 6] = ss;
  __syncthreads();
  const float r = rsqrtf((red[0] + red[1] + red[2] + red[3]) * (1.f / 1024.f) + RMS_EPS);
  const float4 gv = ((const float4*)g)[t];
  bf16x4 o;
  o[0] = (bf16_t)(v.x * r * gv.x); o[1] = (bf16_t)(v.y * r * gv.y);
  o[2] = (bf16_t)(v.z * r * gv.z); o[3] = (bf16_t)(v.w * r * gv.w);
  *(bf16x4*)(xn + (size_t)m * 1024 + t * 4) = o;
}

// ---------- deep-ring NT GEMM: C[m,n] = sum_k A[m,k]*B[n,k] ----------
// BM=128, BN=256, BK=32, 8 waves (2Mx4N), ring-4 K-tile LDS, counted vmcnt,
// both-sides swizzle, setprio around MFMA cluster.
// MODE 0: +bias -> bf16 out; MODE 1: +bias->gelu->bf16; MODE 2: +bias+bf16resid->f32
template <int MODE>
__global__ __launch_bounds__(512, 2) void gemm2(const bf16_t* __restrict__ A,
                                                const bf16_t* __restrict__ Bm,
                                                const float* __restrict__ bias,
                                                const bf16_t* __restrict__ residb,
                                                void* __restrict__ outp,
                                                int M, int N, int K) {
  __shared__ bf16_t As[4][128][32];   // 32 KB
  __shared__ bf16_t Bs[4][256][32];   // 64 KB
  const int t = threadIdx.x;
  const int lane = t & 63;
  const int w = t >> 6;        // 0..7
  const int wm = w >> 2;       // 0..1  (row half)
  const int wn = w & 3;        // 0..3  (col quarter)
  const int nTN = N >> 8;

  // bijective XCD swizzle (grids are multiples of 8)
  const int nwg = gridDim.x;
  const int cpx = nwg >> 3;
  int bid = blockIdx.x;
  bid = (bid & 7) * cpx + (bid >> 3);
  const int tm = bid / nTN, tn = bid % nTN;

  const size_t sK = (size_t)K;
  const int NT = K >> 5;

  // ---- staging source pointers (pre-swizzled global, linear LDS dest) ----
  // thread covers tile row sr, 16B chunk; logical col = chunk^(row&3) swizzle
  const int sr = w * 16 + (lane >> 2);                       // 0..127
  const int ssw = (((lane & 3) ^ ((lane >> 2) & 3)) << 3);   // swizzled col elem
  const bf16_t* gA  = A  + ((size_t)tm * 128 + sr) * sK + ssw;
  const bf16_t* gB0 = Bm + ((size_t)tn * 256 + sr) * sK + ssw;
  const bf16_t* gB1 = gB0 + (size_t)128 * sK;               // rows 128..255 (same swz: (r+128)&3==r&3)

  bf16_t* const AsF = &As[0][0][0];
  bf16_t* const BsF = &Bs[0][0][0];
  bf16_t* const dA  = &As[0][w * 16][0];          // + slot*4096 elems
  bf16_t* const dB0 = &Bs[0][w * 16][0];          // + slot*8192 elems
  bf16_t* const dB1 = &Bs[0][128 + w * 16][0];

  // ---- ds_read fragment addressing (swizzled) ----
  const int r16 = lane & 15, g4 = lane >> 4;
  const int scol = ((g4 ^ (r16 & 3)) << 3);
  const int loA = (wm * 64 + r16) * 32 + scol;
  const int loB = (wn * 64 + r16) * 32 + scol;

  f32x4 acc[4][4];
  #pragma unroll
  for (int i = 0; i < 4; ++i)
    #pragma unroll
    for (int j = 0; j < 4; ++j) acc[i][j] = (f32x4){0.f, 0.f, 0.f, 0.f};

  auto STAGE = [&](int tt) {
    const int sl = tt & 3;
    const size_t ko = (size_t)tt << 5;
    gload16(gA  + ko, dA  + sl * 4096);
    gload16(gB0 + ko, dB0 + sl * 8192);
    gload16(gB1 + ko, dB1 + sl * 8192);
  };
  auto READ = [&](int tt, bf16x8* aa, bf16x8* bb) {
    const int sl = tt & 3;
    const bf16_t* pa = AsF + sl * 4096 + loA;
    const bf16_t* pb = BsF + sl * 8192 + loB;
    aa[0] = *(const bf16x8*)(pa);        aa[1] = *(const bf16x8*)(pa + 512);
    aa[2] = *(const bf16x8*)(pa + 1024); aa[3] = *(const bf16x8*)(pa + 1536);
    bb[0] = *(const bf16x8*)(pb);        bb[1] = *(const bf16x8*)(pb + 512);
    bb[2] = *(const bf16x8*)(pb + 1024); bb[3] = *(const bf16x8*)(pb + 1536);
  };
  auto BODY = [&](int tt, bf16x8* ca, bf16x8* cb, bf16x8* na, bf16x8* nb) {
    // stage tile tt+3 (slot of tile tt-1, whose reads ended before last barrier)
    if (tt + 4 <= NT) {
      STAGE(tt + 3);
      asm volatile("s_waitcnt vmcnt(6)" ::: "memory");   // tile tt+1 landed; 2 tiles in flight
    } else if (tt == NT - 3) {
      asm volatile("s_waitcnt vmcnt(3)" ::: "memory");
    } else if (tt == NT - 2) {
      asm volatile("s_waitcnt vmcnt(0)" ::: "memory");
    }
    __syncthreads();                                      // tile tt+1 visible to all waves
    if (tt + 1 < NT) READ(tt + 1, na, nb);                // prefetch frags (overlaps MFMA below)
    __builtin_amdgcn_s_setprio(1);
    #pragma unroll
    for (int mi = 0; mi < 4; ++mi)
      #pragma unroll
      for (int nj = 0; nj < 4; ++nj)
        acc[mi][nj] = __builtin_amdgcn_mfma_f32_16x16x32_bf16(ca[mi], cb[nj], acc[mi][nj], 0, 0, 0);
    __builtin_amdgcn_s_setprio(0);
  };

  bf16x8 fa0[4], fb0[4], fa1[4], fb1[4];
  // prologue: stage tiles 0..2, wait tile 0, read frags of tile 0
  STAGE(0); STAGE(1); STAGE(2);
  asm volatile("s_waitcnt vmcnt(6)" ::: "memory");
  __syncthreads();
  READ(0, fa0, fb0);
  for (int tt = 0; tt < NT; tt += 2) {   // NT even (K=1024 -> 32)
    BODY(tt,     fa0, fb0, fa1, fb1);
    BODY(tt + 1, fa1, fb1, fa0, fb0);
  }

  // epilogue: C/D layout col = lane&15, row = (lane>>4)*4 + reg
  const int hi4 = g4 * 4;
  #pragma unroll
  for (int mi = 0; mi < 4; ++mi) {
    #pragma unroll
    for (int nj = 0; nj < 4; ++nj) {
      const int gc = tn * 256 + wn * 64 + nj * 16 + r16;
      const float bv = bias[gc];
      #pragma unroll
      for (int r = 0; r < 4; ++r) {
        const int gr = tm * 128 + wm * 64 + mi * 16 + hi4 + r;
        float v = acc[mi][nj][r] + bv;
        if constexpr (MODE == 0) {
          ((bf16_t*)outp)[(size_t)gr * N + gc] = (bf16_t)v;
        } else if constexpr (MODE == 1) {
          v = 0.5f * v * (1.0f + erff(v * 0.70710678118654752f));
          ((bf16_t*)outp)[(size_t)gr * N + gc] = (bf16_t)v;
        } else {
          v += (float)residb[(size_t)gr * N + gc];
          ((float*)outp)[(size_t)gr * N + gc] = v;
        }
      }
    }
  }
}

// ---------- fused differential linear attention, one wave per position ----------
__global__ __launch_bounds__(256) void attn_fused(const bf16_t* __restrict__ qkv,
                                                  const float* __restrict__ lp,
                                                  const float* __restrict__ g2,
                                                  const float* __restrict__ g3,
                                                  bf16_t* __restrict__ attnb) {
  __shared__ __align__(16) char lds[4][6656];
  const int t = threadIdx.x;
  const int lane = t & 63;
  const int w = t >> 6;
  const int m = blockIdx.x * 4 + w;
  char* const sQ  = lds[w];          // [16 h][64 d] bf16, 128B rows, swz ((h&7)<<4)
  char* const sK  = lds[w] + 2048;   // same layout
  char* const sVt = lds[w] + 4096;   // [64 e][16 h'] bf16, 32B rows, swz ((e&1)<<4)
  char* const sSb = lds[w] + 6144;   // [16 h][16 h'] bf16, 32B rows, swz ((h&1)<<4)

  const float lmbda = __expf(lp[0] * lp[1]) - __expf(lp[2] * lp[3]) + 0.2f;
  const int l7 = lane & 7, l8 = lane >> 3;
  const bf16x8* src = (const bf16x8*)(qkv + (size_t)m * 3072);

  const float qsc = (l7 < 4) ? KV_SCALE : -lmbda * KV_SCALE;
  #pragma unroll
  for (int c = 0; c < 2; ++c) {
    bf16x8 v = src[c * 64 + lane];
    const int h = c * 8 + l8;
    bf16x8 o;
    #pragma unroll
    for (int i = 0; i < 8; ++i) {
      float f = (float)v[i];
      f = f > 0.f ? f : __expf(f) - 1.f;
      o[i] = (bf16_t)(f * qsc);
    }
    *(bf16x8*)(sQ + ((h * 128 + 16 * l7) ^ ((h & 7) << 4))) = o;
  }
  #pragma unroll
  for (int c = 2; c < 4; ++c) {
    bf16x8 v = src[c * 64 + lane];
    const int h = (c - 2) * 8 + l8;
    bf16x8 o;
    #pragma unroll
    for (int i = 0; i < 8; ++i) {
      float f = (float)v[i];
      f = f > 0.f ? f : __expf(f) - 1.f;
      o[i] = (bf16_t)f;
    }
    *(bf16x8*)(sK + ((h * 128 + 16 * l7) ^ ((h & 7) << 4))) = o;
  }
  #pragma unroll
  for (int c = 4; c < 6; ++c) {
    bf16x8 v = src[c * 64 + lane];
    const int h = (c - 4) * 8 + l8;
    #pragma unroll
    for (int i = 0; i < 8; ++i) {
      const int e = 8 * l7 + i;
      *(bf16_t*)(sVt + ((e * 32 + h * 2) ^ ((e & 1) << 4))) = v[i];
    }
  }

  const int r16 = lane & 15, g4 = lane >> 4;
  f32x4 accS = {};
  {
    const int ra = r16 * 128;
    const int sw = (r16 & 7) << 4;
    bf16x8 a0 = *(const bf16x8*)(sQ + ((ra + 16 * g4) ^ sw));
    bf16x8 b0 = *(const bf16x8*)(sK + ((ra + 16 * g4) ^ sw));
    bf16x8 a1 = *(const bf16x8*)(sQ + ((ra + 64 + 16 * g4) ^ sw));
    bf16x8 b1 = *(const bf16x8*)(sK + ((ra + 64 + 16 * g4) ^ sw));
    accS = __builtin_amdgcn_mfma_f32_16x16x32_bf16(a0, b0, accS, 0, 0, 0);
    accS = __builtin_amdgcn_mfma_f32_16x16x32_bf16(a1, b1, accS, 0, 0, 0);
  }

  #pragma unroll
  for (int r = 0; r < 4; ++r) {
    const int h = g4 * 4 + r;
    *(bf16_t*)(sSb + ((h * 32 + 2 * r16) ^ ((h & 1) << 4))) = (bf16_t)accS[r];
  }

  bf16x8 zf = {};
  bf16x8 aS = zf;
  if (lane < 32) aS = *(const bf16x8*)(sSb + ((r16 * 32 + 16 * g4) ^ ((r16 & 1) << 4)));
  f32x4 accA[4];
  #pragma unroll
  for (int j = 0; j < 4; ++j) {
    bf16x8 bV = zf;
    if (lane < 32) {
      const int row = j * 16 + r16;
      bV = *(const bf16x8*)(sVt + ((row * 32 + 16 * g4) ^ ((row & 1) << 4)));
    }
    f32x4 z4 = {};
    accA[j] = __builtin_amdgcn_mfma_f32_16x16x32_bf16(aS, bV, z4, 0, 0, 0);
  }

  float rnh[4];
  #pragma unroll
  for (int r = 0; r < 4; ++r) {
    float s = 0.f;
    #pragma unroll
    for (int j = 0; j < 4; ++j) s += accA[j][r] * accA[j][r];
    #pragma unroll
    for (int o = 1; o < 16; o <<= 1) s += __shfl_xor(s, o);
    rnh[r] = rsqrtf(s * (1.f / 64.f) + RMS_EPS);
  }
  float g2v[4];
  #pragma unroll
  for (int j = 0; j < 4; ++j) g2v[j] = g2[j * 16 + r16];
  float val[4][4];
  float tot = 0.f;
  #pragma unroll
  for (int j = 0; j < 4; ++j)
    #pragma unroll
    for (int r = 0; r < 4; ++r) {
      const float vv = accA[j][r] * rnh[r] * g2v[j] * 0.8f;
      val[j][r] = vv;
      tot += vv * vv;
    }
  #pragma unroll
  for (int o = 1; o < 64; o <<= 1) tot += __shfl_xor(tot, o);
  const float rn2 = rsqrtf(tot * (1.f / 1024.f) + RMS_EPS);

  bf16_t* dst = attnb + (size_t)m * 1024;
  #pragma unroll
  for (int j = 0; j < 4; ++j)
    #pragma unroll
    for (int r = 0; r < 4; ++r) {
      const int n = (g4 * 4 + r) * 64 + j * 16 + r16;
      const float ov = val[j][r] * rn2 * g3[n] + val[j][r];
      dst[n] = (bf16_t)ov;
    }
}

extern "C" void kernel_launch(void* const* d_in, const int* in_sizes, int n_in,
                              void* d_out, int out_size, void* d_ws, size_t ws_size,
                              hipStream_t stream) {
  const float* x   = (const float*)d_in[0];
  const float* Wq  = (const float*)d_in[1];
  const float* bq  = (const float*)d_in[2];
  const float* Wk  = (const float*)d_in[3];
  const float* bk  = (const float*)d_in[4];
  const float* Wv  = (const float*)d_in[5];
  const float* bv  = (const float*)d_in[6];
  const float* lp  = (const float*)d_in[7];
  const float* g1  = (const float*)d_in[8];
  const float* g2  = (const float*)d_in[9];
  const float* g3  = (const float*)d_in[10];
  const float* Wf1 = (const float*)d_in[11];
  const float* bf1 = (const float*)d_in[12];
  const float* Wf2 = (const float*)d_in[13];
  const float* bf2 = (const float*)d_in[14];

  char* ws = (char*)d_ws;
  bf16_t* wqkv  = (bf16_t*)(ws + 0);           // [3072][1024] bf16 (Wq,Wk,Wv)
  bf16_t* wf1b  = (bf16_t*)(ws + 6291456);     // [1024][1024] bf16
  bf16_t* wf2b  = (bf16_t*)(ws + 8388608);     // [1024][1024] bf16
  float*  bqkv  = (float*)(ws + 10485760);     // [3072] f32
  bf16_t* xn    = (bf16_t*)(ws + 10498048);    // [8192][1024] bf16
  bf16_t* qkv   = (bf16_t*)(ws + 27275264);    // [8192][3072] bf16
  bf16_t* attnb = (bf16_t*)(ws + 77606912);    // [8192][1024] bf16
  bf16_t* hbuf  = (bf16_t*)(ws + 94384128);    // [8192][1024] bf16

  cast_all<<<dim3(1024, 5), 256, 0, stream>>>(Wq, Wk, Wv, Wf1, Wf2, wqkv);
  concat_bias<<<12, 256, 0, stream>>>(bq, bk, bv, bqkv);
  rmsnorm_x<<<8192, 256, 0, stream>>>(x, g1, xn);
  gemm2<0><<<768, 512, 0, stream>>>(xn, wqkv, bqkv, nullptr, (void*)qkv, 8192, 3072, 1024);
  attn_fused<<<2048, 256, 0, stream>>>(qkv, lp, g2, g3, attnb);
  gemm2<1><<<256, 512, 0, stream>>>(attnb, wf1b, bf1, nullptr, (void*)hbuf, 8192, 1024, 1024);
  gemm2<2><<<256, 512, 0, stream>>>(hbuf, wf2b, bf2, attnb, d_out, 8192, 1024, 1024);
}

// Round 4
// 260.587 us; speedup vs baseline: 1.1108x; 1.1108x over previous
//
#include <hip/hip_runtime.h>
#include <cmath>

typedef __bf16 bf16_t;
typedef __attribute__((ext_vector_type(8))) __bf16 bf16x8;
typedef __attribute__((ext_vector_type(4))) __bf16 bf16x4;
typedef __attribute__((ext_vector_type(4))) float f32x4;

#define RMS_EPS 1.1920929e-07f
#define KV_SCALE 0.04419417382415922f   // 1/sqrt(512)

__device__ __forceinline__ void gload16(const void* g, void* l) {
  __builtin_amdgcn_global_load_lds((const __attribute__((address_space(1))) void*)g,
                                   (__attribute__((address_space(3))) void*)l, 16, 0, 0);
}

// ---------- all 5 weight casts in one launch: grid (1024, 5) x 256 ----------
__global__ __launch_bounds__(256) void cast_all(const float* __restrict__ s0,
                                                const float* __restrict__ s1,
                                                const float* __restrict__ s2,
                                                const float* __restrict__ s3,
                                                const float* __restrict__ s4,
                                                bf16_t* __restrict__ d) {
  const float* srcs[5] = {s0, s1, s2, s3, s4};
  const int which = blockIdx.y;
  const float* src = srcs[which];
  bf16_t* dst = d + ((size_t)which << 20);
  int i = (blockIdx.x * 256 + threadIdx.x) * 4;
  float4 v = *(const float4*)(src + i);
  bf16x4 o;
  o[0] = (bf16_t)v.x; o[1] = (bf16_t)v.y; o[2] = (bf16_t)v.z; o[3] = (bf16_t)v.w;
  *(bf16x4*)(dst + i) = o;
}

__global__ void concat_bias(const float* __restrict__ bq, const float* __restrict__ bk,
                            const float* __restrict__ bv, float* __restrict__ dst) {
  int i = blockIdx.x * 256 + threadIdx.x;   // grid 12*256 = 3072
  float v;
  if (i < 1024) v = bq[i];
  else if (i < 2048) v = bk[i - 1024];
  else v = bv[i - 2048];
  dst[i] = v;
}

// ---------- RMSNorm(x, g1) -> bf16, one block per row of 1024 ----------
__global__ __launch_bounds__(256) void rmsnorm_x(const float* __restrict__ x,
                                                 const float* __restrict__ g,
                                                 bf16_t* __restrict__ xn) {
  const int m = blockIdx.x, t = threadIdx.x;
  const float4 v = ((const float4*)(x + (size_t)m * 1024))[t];
  float ss = v.x * v.x + v.y * v.y + v.z * v.z + v.w * v.w;
  #pragma unroll
  for (int o = 1; o < 64; o <<= 1) ss += __shfl_xor(ss, o);
  __shared__ float red[4];
  if ((t & 63) == 0) red[t >> 6] = ss;
  __syncthreads();
  const float r = rsqrtf((red[0] + red[1] + red[2] + red[3]) * (1.f / 1024.f) + RMS_EPS);
  const float4 gv = ((const float4*)g)[t];
  bf16x4 o;
  o[0] = (bf16_t)(v.x * r * gv.x); o[1] = (bf16_t)(v.y * r * gv.y);
  o[2] = (bf16_t)(v.z * r * gv.z); o[3] = (bf16_t)(v.w * r * gv.w);
  *(bf16x4*)(xn + (size_t)m * 1024 + t * 4) = o;
}

// ---------- ring-3 NT GEMM, raw s_barrier + counted vmcnt ----------
// BM=BN=128, BK=32, 4 waves (2Mx2N), 48KB LDS -> 3 blocks/CU.
// Swizzle: LDS chunk' = chunk ^ ((row>>1)&3); applied on pre-swizzled global
// source (linear gload_lds dest) AND on ds_read addr (rule #21).
// MODE 0: +bias -> bf16; MODE 1: +bias->gelu->bf16; MODE 2: +bias+bf16resid->f32
template <int MODE>
__global__ __launch_bounds__(256, 3) void gemm3(const bf16_t* __restrict__ A,
                                                const bf16_t* __restrict__ Bm,
                                                const float* __restrict__ bias,
                                                const bf16_t* __restrict__ residb,
                                                void* __restrict__ outp,
                                                int M, int N, int K) {
  __shared__ bf16_t As[3][128][32];   // 24 KB
  __shared__ bf16_t Bs[3][128][32];   // 24 KB
  const int t = threadIdx.x;
  const int lane = t & 63;
  const int w = t >> 6;        // 0..3
  const int wm = w >> 1, wn = w & 1;
  const int nTN = N >> 7;

  // bijective XCD swizzle (grids are multiples of 8)
  const int nwg = gridDim.x;
  const int cpx = nwg >> 3;
  int bid = blockIdx.x;
  bid = (bid & 7) * cpx + (bid >> 3);
  const int tm = bid / nTN, tn = bid % nTN;

  const size_t sK = (size_t)K;
  const int NT = K >> 5;       // 32

  // staging: thread covers LDS row sr, 16B chunk (t&3); global col pre-swizzled
  const int sr = t >> 2;                                     // 0..63 (+64 for 2nd)
  const int ssw = (((t & 3) ^ ((t >> 3) & 3)) << 3);         // elems
  const bf16_t* gA  = A  + ((size_t)tm * 128 + sr) * sK + ssw;
  const bf16_t* gA1 = gA + (size_t)64 * sK;
  const bf16_t* gB  = Bm + ((size_t)tn * 128 + sr) * sK + ssw;
  const bf16_t* gB1 = gB + (size_t)64 * sK;
  bf16_t* const dA0 = &As[0][w * 16][0];       // wave-uniform bases (+slot*4096)
  bf16_t* const dA1 = &As[0][64 + w * 16][0];
  bf16_t* const dB0 = &Bs[0][w * 16][0];
  bf16_t* const dB1 = &Bs[0][64 + w * 16][0];
  bf16_t* const AsF = &As[0][0][0];
  bf16_t* const BsF = &Bs[0][0][0];

  // ds_read fragment addressing (swizzled): row = ..+r16, chunk g4^((r16>>1)&3)
  const int r16 = lane & 15, g4 = lane >> 4;
  const int scol = ((g4 ^ ((r16 >> 1) & 3)) << 3);
  const int loA = (wm * 64 + r16) * 32 + scol;
  const int loB = (wn * 64 + r16) * 32 + scol;

  f32x4 acc[4][4];
  #pragma unroll
  for (int i = 0; i < 4; ++i)
    #pragma unroll
    for (int j = 0; j < 4; ++j) acc[i][j] = (f32x4){0.f, 0.f, 0.f, 0.f};

  auto STAGE = [&](int tt, int sl) {
    const size_t ko = (size_t)tt << 5;
    const int so = sl * 4096;
    gload16(gA  + ko, dA0 + so);
    gload16(gA1 + ko, dA1 + so);
    gload16(gB  + ko, dB0 + so);
    gload16(gB1 + ko, dB1 + so);
  };
  auto READ = [&](int sl, bf16x8* aa, bf16x8* bb) {
    const bf16_t* pa = AsF + sl * 4096 + loA;
    const bf16_t* pb = BsF + sl * 4096 + loB;
    aa[0] = *(const bf16x8*)(pa);        aa[1] = *(const bf16x8*)(pa + 512);
    aa[2] = *(const bf16x8*)(pa + 1024); aa[3] = *(const bf16x8*)(pa + 1536);
    bb[0] = *(const bf16x8*)(pb);        bb[1] = *(const bf16x8*)(pb + 512);
    bb[2] = *(const bf16x8*)(pb + 1024); bb[3] = *(const bf16x8*)(pb + 1536);
  };

  int sl_w = 2;   // slot for tile tt+2
  int sl_r = 1;   // slot holding tile tt+1
  auto BODY = [&](int tt, bf16x8* ca, bf16x8* cb, bf16x8* na, bf16x8* nb) {
    if (tt + 2 < NT) {
      STAGE(tt + 2, sl_w);
      sl_w = (sl_w == 2) ? 0 : sl_w + 1;
      asm volatile("s_waitcnt vmcnt(4)" ::: "memory");   // tile tt+1 landed; tt+2 in flight
    } else if (tt + 2 == NT) {
      asm volatile("s_waitcnt vmcnt(0)" ::: "memory");   // last tile landed
    }
    asm volatile("" ::: "memory");
    __builtin_amdgcn_s_barrier();                        // raw: no vmcnt drain
    asm volatile("" ::: "memory");
    if (tt + 1 < NT) {
      READ(sl_r, na, nb);                                // overlaps MFMA below
      sl_r = (sl_r == 2) ? 0 : sl_r + 1;
    }
    __builtin_amdgcn_s_setprio(1);
    #pragma unroll
    for (int mi = 0; mi < 4; ++mi)
      #pragma unroll
      for (int nj = 0; nj < 4; ++nj)
        acc[mi][nj] = __builtin_amdgcn_mfma_f32_16x16x32_bf16(ca[mi], cb[nj], acc[mi][nj], 0, 0, 0);
    __builtin_amdgcn_s_setprio(0);
  };

  bf16x8 fa0[4], fb0[4], fa1[4], fb1[4];
  STAGE(0, 0); STAGE(1, 1);
  asm volatile("s_waitcnt vmcnt(4)" ::: "memory");       // tile 0 landed
  asm volatile("" ::: "memory");
  __builtin_amdgcn_s_barrier();
  asm volatile("" ::: "memory");
  READ(0, fa0, fb0);
  for (int tt = 0; tt < NT; tt += 2) {                   // NT = 32 (even)
    BODY(tt,     fa0, fb0, fa1, fb1);
    BODY(tt + 1, fa1, fb1, fa0, fb0);
  }

  // epilogue: C/D layout col = lane&15, row = (lane>>4)*4 + reg
  const int hi4 = g4 * 4;
  #pragma unroll
  for (int mi = 0; mi < 4; ++mi) {
    #pragma unroll
    for (int nj = 0; nj < 4; ++nj) {
      const int gc = tn * 128 + wn * 64 + nj * 16 + r16;
      const float bv = bias[gc];
      #pragma unroll
      for (int r = 0; r < 4; ++r) {
        const int gr = tm * 128 + wm * 64 + mi * 16 + hi4 + r;
        float v = acc[mi][nj][r] + bv;
        if constexpr (MODE == 0) {
          ((bf16_t*)outp)[(size_t)gr * N + gc] = (bf16_t)v;
        } else if constexpr (MODE == 1) {
          v = 0.5f * v * (1.0f + erff(v * 0.70710678118654752f));
          ((bf16_t*)outp)[(size_t)gr * N + gc] = (bf16_t)v;
        } else {
          v += (float)residb[(size_t)gr * N + gc];
          ((float*)outp)[(size_t)gr * N + gc] = v;
        }
      }
    }
  }
}

// ---------- fused differential linear attention, one wave per position ----------
__global__ __launch_bounds__(256) void attn_fused(const bf16_t* __restrict__ qkv,
                                                  const float* __restrict__ lp,
                                                  const float* __restrict__ g2,
                                                  const float* __restrict__ g3,
                                                  bf16_t* __restrict__ attnb) {
  __shared__ __align__(16) char lds[4][6656];
  const int t = threadIdx.x;
  const int lane = t & 63;
  const int w = t >> 6;
  const int m = blockIdx.x * 4 + w;
  char* const sQ  = lds[w];          // [16 h][64 d] bf16, 128B rows, swz ((h&7)<<4)
  char* const sK  = lds[w] + 2048;   // same layout
  char* const sVt = lds[w] + 4096;   // [64 e][16 h'] bf16, 32B rows, swz ((e&1)<<4)
  char* const sSb = lds[w] + 6144;   // [16 h][16 h'] bf16, 32B rows, swz ((h&1)<<4)

  const float lmbda = __expf(lp[0] * lp[1]) - __expf(lp[2] * lp[3]) + 0.2f;
  const int l7 = lane & 7, l8 = lane >> 3;
  const bf16x8* src = (const bf16x8*)(qkv + (size_t)m * 3072);

  const float qsc = (l7 < 4) ? KV_SCALE : -lmbda * KV_SCALE;
  #pragma unroll
  for (int c = 0; c < 2; ++c) {
    bf16x8 v = src[c * 64 + lane];
    const int h = c * 8 + l8;
    bf16x8 o;
    #pragma unroll
    for (int i = 0; i < 8; ++i) {
      float f = (float)v[i];
      f = f > 0.f ? f : __expf(f) - 1.f;
      o[i] = (bf16_t)(f * qsc);
    }
    *(bf16x8*)(sQ + ((h * 128 + 16 * l7) ^ ((h & 7) << 4))) = o;
  }
  #pragma unroll
  for (int c = 2; c < 4; ++c) {
    bf16x8 v = src[c * 64 + lane];
    const int h = (c - 2) * 8 + l8;
    bf16x8 o;
    #pragma unroll
    for (int i = 0; i < 8; ++i) {
      float f = (float)v[i];
      f = f > 0.f ? f : __expf(f) - 1.f;
      o[i] = (bf16_t)f;
    }
    *(bf16x8*)(sK + ((h * 128 + 16 * l7) ^ ((h & 7) << 4))) = o;
  }
  #pragma unroll
  for (int c = 4; c < 6; ++c) {
    bf16x8 v = src[c * 64 + lane];
    const int h = (c - 4) * 8 + l8;
    #pragma unroll
    for (int i = 0; i < 8; ++i) {
      const int e = 8 * l7 + i;
      *(bf16_t*)(sVt + ((e * 32 + h * 2) ^ ((e & 1) << 4))) = v[i];
    }
  }

  const int r16 = lane & 15, g4 = lane >> 4;
  f32x4 accS = {};
  {
    const int ra = r16 * 128;
    const int sw = (r16 & 7) << 4;
    bf16x8 a0 = *(const bf16x8*)(sQ + ((ra + 16 * g4) ^ sw));
    bf16x8 b0 = *(const bf16x8*)(sK + ((ra + 16 * g4) ^ sw));
    bf16x8 a1 = *(const bf16x8*)(sQ + ((ra + 64 + 16 * g4) ^ sw));
    bf16x8 b1 = *(const bf16x8*)(sK + ((ra + 64 + 16 * g4) ^ sw));
    accS = __builtin_amdgcn_mfma_f32_16x16x32_bf16(a0, b0, accS, 0, 0, 0);
    accS = __builtin_amdgcn_mfma_f32_16x16x32_bf16(a1, b1, accS, 0, 0, 0);
  }

  #pragma unroll
  for (int r = 0; r < 4; ++r) {
    const int h = g4 * 4 + r;
    *(bf16_t*)(sSb + ((h * 32 + 2 * r16) ^ ((h & 1) << 4))) = (bf16_t)accS[r];
  }

  bf16x8 zf = {};
  bf16x8 aS = zf;
  if (lane < 32) aS = *(const bf16x8*)(sSb + ((r16 * 32 + 16 * g4) ^ ((r16 & 1) << 4)));
  f32x4 accA[4];
  #pragma unroll
  for (int j = 0; j < 4; ++j) {
    bf16x8 bV = zf;
    if (lane < 32) {
      const int row = j * 16 + r16;
      bV = *(const bf16x8*)(sVt + ((row * 32 + 16 * g4) ^ ((row & 1) << 4)));
    }
    f32x4 z4 = {};
    accA[j] = __builtin_amdgcn_mfma_f32_16x16x32_bf16(aS, bV, z4, 0, 0, 0);
  }

  float rnh[4];
  #pragma unroll
  for (int r = 0; r < 4; ++r) {
    float s = 0.f;
    #pragma unroll
    for (int j = 0; j < 4; ++j) s += accA[j][r] * accA[j][r];
    #pragma unroll
    for (int o = 1; o < 16; o <<= 1) s += __shfl_xor(s, o);
    rnh[r] = rsqrtf(s * (1.f / 64.f) + RMS_EPS);
  }
  float g2v[4];
  #pragma unroll
  for (int j = 0; j < 4; ++j) g2v[j] = g2[j * 16 + r16];
  float val[4][4];
  float tot = 0.f;
  #pragma unroll
  for (int j = 0; j < 4; ++j)
    #pragma unroll
    for (int r = 0; r < 4; ++r) {
      const float vv = accA[j][r] * rnh[r] * g2v[j] * 0.8f;
      val[j][r] = vv;
      tot += vv * vv;
    }
  #pragma unroll
  for (int o = 1; o < 64; o <<= 1) tot += __shfl_xor(tot, o);
  const float rn2 = rsqrtf(tot * (1.f / 1024.f) + RMS_EPS);

  bf16_t* dst = attnb + (size_t)m * 1024;
  #pragma unroll
  for (int j = 0; j < 4; ++j)
    #pragma unroll
    for (int r = 0; r < 4; ++r) {
      const int n = (g4 * 4 + r) * 64 + j * 16 + r16;
      const float ov = val[j][r] * rn2 * g3[n] + val[j][r];
      dst[n] = (bf16_t)ov;
    }
}

extern "C" void kernel_launch(void* const* d_in, const int* in_sizes, int n_in,
                              void* d_out, int out_size, void* d_ws, size_t ws_size,
                              hipStream_t stream) {
  const float* x   = (const float*)d_in[0];
  const float* Wq  = (const float*)d_in[1];
  const float* bq  = (const float*)d_in[2];
  const float* Wk  = (const float*)d_in[3];
  const float* bk  = (const float*)d_in[4];
  const float* Wv  = (const float*)d_in[5];
  const float* bv  = (const float*)d_in[6];
  const float* lp  = (const float*)d_in[7];
  const float* g1  = (const float*)d_in[8];
  const float* g2  = (const float*)d_in[9];
  const float* g3  = (const float*)d_in[10];
  const float* Wf1 = (const float*)d_in[11];
  const float* bf1 = (const float*)d_in[12];
  const float* Wf2 = (const float*)d_in[13];
  const float* bf2 = (const float*)d_in[14];

  char* ws = (char*)d_ws;
  bf16_t* wqkv  = (bf16_t*)(ws + 0);           // [3072][1024] bf16 (Wq,Wk,Wv)
  bf16_t* wf1b  = (bf16_t*)(ws + 6291456);     // [1024][1024] bf16
  bf16_t* wf2b  = (bf16_t*)(ws + 8388608);     // [1024][1024] bf16
  float*  bqkv  = (float*)(ws + 10485760);     // [3072] f32
  bf16_t* xn    = (bf16_t*)(ws + 10498048);    // [8192][1024] bf16
  bf16_t* qkv   = (bf16_t*)(ws + 27275264);    // [8192][3072] bf16
  bf16_t* attnb = (bf16_t*)(ws + 77606912);    // [8192][1024] bf16
  bf16_t* hbuf  = (bf16_t*)(ws + 94384128);    // [8192][1024] bf16

  cast_all<<<dim3(1024, 5), 256, 0, stream>>>(Wq, Wk, Wv, Wf1, Wf2, wqkv);
  concat_bias<<<12, 256, 0, stream>>>(bq, bk, bv, bqkv);
  rmsnorm_x<<<8192, 256, 0, stream>>>(x, g1, xn);
  gemm3<0><<<1536, 256, 0, stream>>>(xn, wqkv, bqkv, nullptr, (void*)qkv, 8192, 3072, 1024);
  attn_fused<<<2048, 256, 0, stream>>>(qkv, lp, g2, g3, attnb);
  gemm3<1><<<512, 256, 0, stream>>>(attnb, wf1b, bf1, nullptr, (void*)hbuf, 8192, 1024, 1024);
  gemm3<2><<<512, 256, 0, stream>>>(hbuf, wf2b, bf2, attnb, d_out, 8192, 1024, 1024);
}